// Round 1
// 423.342 us; speedup vs baseline: 1.0867x; 1.0867x over previous
//
#include <hip/hip_runtime.h>

typedef _Float16 half8 __attribute__((ext_vector_type(8)));
typedef float floatx4 __attribute__((ext_vector_type(4)));
typedef unsigned uint4v __attribute__((ext_vector_type(4)));

#define Bsz 512
#define Tsz 168
#define Fsz 16
#define Hsz 256
#define KTILES 9      // K = 288 = 9 * 32  (256 h + 16 x + 16 zero pad)
#define LDS_K 296     // padded LDS row stride in halves

// workspace layout (bytes, all 16B aligned)
#define WSW_OFF   0          // swizzled [w_hh|w_ih|0] f16 frags: 64nt*9kt*64lane*16B = 589824
#define BIAS_OFF  589824     // reordered (b_ih+b_hh) fp32: 1024*4 = 4096
#define FC1_OFF   593920     // fc1 frags: 8nt*8kt*64*16B = 65536
#define FC2_OFF   659456     // fc2 frags: 4nt*4kt*64*16B = 16384
#define HH_OFF    675840     // h history f16 [B][T][H]: 512*168*256*2 = 44040192
#define XBUF_OFF  (HH_OFF + 44040192)   // tagged exchange ring: 32bb*2*16m*128slot*8B = 1 MB

// ---------------- fused prep: all weight swizzles + bias in ONE launch -----
__global__ __launch_bounds__(256) void k_prep(
    const float* __restrict__ w_hh, const float* __restrict__ w_ih,
    const float* __restrict__ b_ih, const float* __restrict__ b_hh,
    const float* __restrict__ fc1_w, const float* __restrict__ fc2_w,
    _Float16* __restrict__ wsw, float* __restrict__ bias,
    _Float16* __restrict__ w1f, _Float16* __restrict__ w2f) {
    const int b = blockIdx.x, tid = threadIdx.x;
    const int lane = tid & 63, sub = tid >> 6;
    if (b < 144) {                         // w_hh|w_ih swizzle: 576 tiles
        int tile = b * 4 + sub;            // nt*9 + kt
        int nt = tile / KTILES, kt = tile - nt * KTILES;
        int n_in = lane & 15, kg = lane >> 4;
        int J = nt >> 2, g = nt & 3;
        int n_orig = g * 256 + J * 16 + n_in;
        half8 v;
#pragma unroll
        for (int e = 0; e < 8; ++e) {
            int k = kt * 32 + kg * 8 + e;
            float f;
            if (k < 256)      f = w_hh[n_orig * 256 + k];
            else if (k < 272) f = w_ih[n_orig * 16 + (k - 256)];
            else              f = 0.0f;
            v[e] = (_Float16)f;
        }
        ((half8*)wsw)[tile * 64 + lane] = v;
    } else if (b < 148) {                  // bias reorder: 1024
        int id = (b - 144) * 256 + tid;
        int nt = id >> 4, n = id & 15;
        int J = nt >> 2, g = nt & 3;
        int n_orig = g * 256 + J * 16 + n;
        bias[id] = b_ih[n_orig] + b_hh[n_orig];
    } else if (b < 164) {                  // fc1 swizzle: 64 tiles (8nt x 8kt)
        int tile = (b - 148) * 4 + sub;
        int nt = tile >> 3, kt = tile & 7;
        int n_in = lane & 15, kg = lane >> 4;
        half8 v;
#pragma unroll
        for (int e = 0; e < 8; ++e)
            v[e] = (_Float16)fc1_w[(nt * 16 + n_in) * 256 + kt * 32 + kg * 8 + e];
        ((half8*)w1f)[tile * 64 + lane] = v;
    } else {                               // fc2 swizzle: 16 tiles (4nt x 4kt)
        int tile = (b - 164) * 4 + sub;
        int nt = tile >> 2, kt = tile & 3;
        int n_in = lane & 15, kg = lane >> 4;
        half8 v;
#pragma unroll
        for (int e = 0; e < 8; ++e)
            v[e] = (_Float16)fc2_w[(nt * 16 + n_in) * 128 + kt * 32 + kg * 8 + e];
        ((half8*)w2f)[tile * 64 + lane] = v;
    }
}

// ---------------- recurrent LSTM v14: v13 + B-frags in REGISTERS -----------
// R13 counters: MfmaUtil 5.4, VALUBusy 16, 5400 cy/step. Budget says the
// largest critical-path term is LDS issue: 16 ds_read_b128/wave/step re-read
// loop-INVARIANT weight frags from wsh. v14: each wave holds its 18 B-frags
// (2 gg x 9 kt = 72 VGPRs) in registers, wsh deleted entirely (128 KB LDS
// freed, staging loop gone). Numerically identical: same f16 frags, same
// MFMA order. Exchange/poll/cell body byte-identical to v13.
__global__ __launch_bounds__(512, 1) void k_lstm14(
    const float* __restrict__ x, const _Float16* __restrict__ wsw,
    const float* __restrict__ bias, unsigned* __restrict__ hh32,
    unsigned long long* __restrict__ xbuf) {
    __shared__ __align__(16) _Float16 h_lds[16][LDS_K];   // h | x | pad
    __shared__ float glds[4][16][68];                     // [gate][m][j_local], pad 68

    const int tid = threadIdx.x;
    const int wave = tid >> 6, lane = tid & 63;
    const int n_in = lane & 15, quad = lane >> 4;
    const int bb = blockIdx.x & 31, ng = blockIdx.x >> 5;   // XCD-colocated swizzle
    const int b0 = bb * 16;
    const int Jl = wave & 3;               // local J-block 0..3
    const int gp = wave >> 2;              // gate pair: 0 -> (i,f), 1 -> (g,o)

    // ---- one-time: this wave's 18 weight B-frags straight into VGPRs ----
    float bs[2];
    half8 wf[2][KTILES];
#pragma unroll
    for (int gg = 0; gg < 2; ++gg) {
        const int nt = ng * 16 + Jl * 4 + gp * 2 + gg;
        bs[gg] = bias[nt * 16 + n_in];
#pragma unroll
        for (int kt = 0; kt < KTILES; ++kt)
            wf[gg][kt] = ((const half8*)wsw)[((size_t)nt * KTILES + kt) * 64 + lane];
    }

    // zero h0 + x + pad, stage x_0
    for (int i = tid; i < 16 * LDS_K; i += 512)
        ((_Float16*)h_lds)[i] = (_Float16)0.0f;
    __syncthreads();
    if (tid < 256) {
        int m = tid >> 4, f = tid & 15;
        h_lds[m][Hsz + f] = (_Float16)x[((b0 + m) * Tsz + 0) * Fsz + f];
    }
    __syncthreads();

    // cell/publish/gather ownership: thread -> (m = tid>>5, slot = tid&31)
    const int cm = tid >> 5, cj = tid & 31;
    float c_st[2] = {0.f, 0.f};

    for (int t = 0; t < Tsz; ++t) {
        // ---- A-frags from LDS; B-frags all from registers ----
        half8 afr[KTILES];
#pragma unroll
        for (int kt = 0; kt < KTILES; ++kt)
            afr[kt] = *(const half8*)&h_lds[n_in][kt * 32 + quad * 8];

        floatx4 acc[2] = {(floatx4){0.f,0.f,0.f,0.f}, (floatx4){0.f,0.f,0.f,0.f}};
#pragma unroll
        for (int gg = 0; gg < 2; ++gg) {
#pragma unroll
            for (int kt = 0; kt < KTILES; ++kt)
                acc[gg] = __builtin_amdgcn_mfma_f32_16x16x32_f16(afr[kt], wf[gg][kt], acc[gg], 0, 0, 0);
        }

        // ---- stage gate pre-activations to LDS ----
#pragma unroll
        for (int gg = 0; gg < 2; ++gg)
#pragma unroll
            for (int r = 0; r < 4; ++r)
                glds[gp * 2 + gg][quad * 4 + r][Jl * 16 + n_in] = acc[gg][r] + bs[gg];
        __syncthreads();   // G1: gates staged; afr reads done -> h_lds writable

        // ---- cell update: thread owns (cm, j_local = 2cj, 2cj+1) ----
        union { _Float16 f[2]; unsigned u; } pk;
#pragma unroll
        for (int e = 0; e < 2; ++e) {
            int jl = 2 * cj + e;
            float ig = glds[0][cm][jl];
            float fg = glds[1][cm][jl];
            float gg_ = glds[2][cm][jl];
            float og = glds[3][cm][jl];
            float si = 1.0f / (1.0f + __expf(-ig));
            float sf = 1.0f / (1.0f + __expf(-fg));
            float tg = 1.0f - 2.0f / (__expf(2.0f * gg_) + 1.0f);
            float so = 1.0f / (1.0f + __expf(-og));
            float c = sf * c_st[e] + si * tg;
            c_st[e] = c;
            float th = 1.0f - 2.0f / (__expf(2.0f * c) + 1.0f);
            pk.f[e] = (_Float16)(so * th);
        }
        // own quarter of h_{t+1} straight into LDS (safe: reads done at G1)
        *(unsigned*)&h_lds[cm][ng * 64 + 2 * cj] = pk.u;

        const size_t rb = ((size_t)((bb * 2 + (t & 1)) * 16));   // ring base (rows)
        if (t + 1 < Tsz) {
            // publish own slot as a single tagged atom {data | t+1} (L2-resident)
            unsigned long long pv = ((unsigned long long)pk.u << 32) | (unsigned)(t + 1);
            __hip_atomic_store(&xbuf[(rb + cm) * 128 + ng * 32 + cj], pv,
                               __ATOMIC_RELAXED, __HIP_MEMORY_SCOPE_AGENT);
        }
        // history write for k_mlp: NON-TEMPORAL -> no L2 allocate, xbuf survives
        __builtin_nontemporal_store(
            pk.u, &hh32[((size_t)(b0 + cm) * Tsz + t) * 128 + ng * 32 + cj]);

        if (t + 1 < Tsz) {
            // prefetch x_{t+1}; ack overlaps the polls below
            float xr = 0.0f;
            if (tid < 256)
                xr = x[((b0 + (tid >> 4)) * Tsz + (t + 1)) * Fsz + (tid & 15)];

            // ---- gather 3 partner quarters: CONCURRENT tagged-atom polls ----
            const unsigned want = (unsigned)(t + 1);
            unsigned long long* p1 = &xbuf[(rb + cm) * 128 + ((ng + 1) & 3) * 32 + cj];
            unsigned long long* p2 = &xbuf[(rb + cm) * 128 + ((ng + 2) & 3) * 32 + cj];
            unsigned long long* p3 = &xbuf[(rb + cm) * 128 + ((ng + 3) & 3) * 32 + cj];
            unsigned long long v1 = __hip_atomic_load(p1, __ATOMIC_RELAXED,
                                                      __HIP_MEMORY_SCOPE_AGENT);
            unsigned long long v2 = __hip_atomic_load(p2, __ATOMIC_RELAXED,
                                                      __HIP_MEMORY_SCOPE_AGENT);
            unsigned long long v3 = __hip_atomic_load(p3, __ATOMIC_RELAXED,
                                                      __HIP_MEMORY_SCOPE_AGENT);
            while ((unsigned)v1 != want || (unsigned)v2 != want || (unsigned)v3 != want) {
                if ((unsigned)v1 != want)
                    v1 = __hip_atomic_load(p1, __ATOMIC_RELAXED, __HIP_MEMORY_SCOPE_AGENT);
                if ((unsigned)v2 != want)
                    v2 = __hip_atomic_load(p2, __ATOMIC_RELAXED, __HIP_MEMORY_SCOPE_AGENT);
                if ((unsigned)v3 != want)
                    v3 = __hip_atomic_load(p3, __ATOMIC_RELAXED, __HIP_MEMORY_SCOPE_AGENT);
            }
            *(unsigned*)&h_lds[cm][((ng + 1) & 3) * 64 + 2 * cj] = (unsigned)(v1 >> 32);
            *(unsigned*)&h_lds[cm][((ng + 2) & 3) * 64 + 2 * cj] = (unsigned)(v2 >> 32);
            *(unsigned*)&h_lds[cm][((ng + 3) & 3) * 64 + 2 * cj] = (unsigned)(v3 >> 32);
            if (tid < 256)
                h_lds[tid >> 4][Hsz + (tid & 15)] = (_Float16)xr;
            __syncthreads();   // G4: full h_{t+1} + x_{t+1} staged
        }
    }
}

// ---------------- MLP head v5: v4 + cross-chunk NT-load pipeline -----------
// v4 lost ~50 us stalling on vmcnt at each chunk head: NT hh loads bypass L2
// (hh is HBM-resident by design) -> ~900 cy latency with nothing in flight.
// v5 double-buffers the 8 uint4v token-frag loads: issue chunk i+1's loads
// BEFORE computing chunk i, so HBM latency hides under fc1/fc2 LDS+MFMA.
__global__ __launch_bounds__(512, 1) void k_mlp5(
    const _Float16* __restrict__ hh, const _Float16* __restrict__ w1f,
    const _Float16* __restrict__ w2f, const float* __restrict__ b1,
    const float* __restrict__ b2, const float* __restrict__ w3,
    const float* __restrict__ b3, float* __restrict__ out) {
    __shared__ __align__(16) _Float16 w1sh[64 * 512];   // 64 KB
    __shared__ __align__(16) _Float16 w2sh[16 * 512];   // 16 KB
    __shared__ _Float16 st1[8][16][136];
    __shared__ _Float16 st2[8][16][72];

    const int tid = threadIdx.x;
    const int wave = tid >> 6, lane = tid & 63;
    const int n_in = lane & 15, quad = lane >> 4;
    const int nchunks = (Bsz * Tsz) / 128;   // 672

    {   // stage fragment tables once (layout already frag-ordered)
        float4* d1 = (float4*)w1sh;
        const float4* s1 = (const float4*)w1f;
#pragma unroll
        for (int it = 0; it < 8; ++it) d1[it * 512 + tid] = s1[it * 512 + tid];
        float4* d2 = (float4*)w2sh;
        const float4* s2 = (const float4*)w2f;
#pragma unroll
        for (int it = 0; it < 2; ++it) d2[it * 512 + tid] = s2[it * 512 + tid];
    }
    __syncthreads();

    uint4v rawA[8], rawB[8];
    // prologue: issue loads for first chunk
    if (blockIdx.x < nchunks) {
        const int tok0 = blockIdx.x * 128 + wave * 16;
#pragma unroll
        for (int kt = 0; kt < 8; ++kt)
            rawA[kt] = __builtin_nontemporal_load(
                (const uint4v*)&hh[(size_t)(tok0 + n_in) * 256 + kt * 32 + quad * 8]);
    }

    for (int chunk = blockIdx.x; chunk < nchunks; chunk += gridDim.x) {
        // issue NEXT chunk's loads first (latency hides under this chunk)
        const int nxt = chunk + gridDim.x;
        if (nxt < nchunks) {
            const int tok0n = nxt * 128 + wave * 16;
#pragma unroll
            for (int kt = 0; kt < 8; ++kt)
                rawB[kt] = __builtin_nontemporal_load(
                    (const uint4v*)&hh[(size_t)(tok0n + n_in) * 256 + kt * 32 + quad * 8]);
        }

        const int tok0 = chunk * 128 + wave * 16;
        half8 afr[8];
#pragma unroll
        for (int kt = 0; kt < 8; ++kt)
            afr[kt] = __builtin_bit_cast(half8, rawA[kt]);

#pragma unroll
        for (int nt = 0; nt < 8; ++nt) {
            floatx4 a = (floatx4){0.f, 0.f, 0.f, 0.f};
#pragma unroll
            for (int kt = 0; kt < 8; ++kt) {
                half8 bfr = *(const half8*)&w1sh[(nt * 8 + kt) * 512 + lane * 8];
                a = __builtin_amdgcn_mfma_f32_16x16x32_f16(afr[kt], bfr, a, 0, 0, 0);
            }
            float bb = b1[nt * 16 + n_in];
#pragma unroll
            for (int r = 0; r < 4; ++r) {
                float v = a[r] + bb;
                st1[wave][quad * 4 + r][nt * 16 + n_in] = (_Float16)(v > 0.f ? v : 0.f);
            }
        }

        half8 a2[4];
#pragma unroll
        for (int kt = 0; kt < 4; ++kt)
            a2[kt] = *(const half8*)&st1[wave][n_in][kt * 32 + quad * 8];
#pragma unroll
        for (int nt = 0; nt < 4; ++nt) {
            floatx4 a = (floatx4){0.f, 0.f, 0.f, 0.f};
#pragma unroll
            for (int kt = 0; kt < 4; ++kt) {
                half8 bfr = *(const half8*)&w2sh[(nt * 4 + kt) * 512 + lane * 8];
                a = __builtin_amdgcn_mfma_f32_16x16x32_f16(a2[kt], bfr, a, 0, 0, 0);
            }
            float bb = b2[nt * 16 + n_in];
#pragma unroll
            for (int r = 0; r < 4; ++r) {
                float v = a[r] + bb;
                st2[wave][quad * 4 + r][nt * 16 + n_in] = (_Float16)(v > 0.f ? v : 0.f);
            }
        }

        float p = 0.0f;
#pragma unroll
        for (int e = 0; e < 16; ++e)
            p += (float)st2[wave][n_in][quad * 16 + e] * w3[quad * 16 + e];
        p += __shfl_down(p, 32);
        p += __shfl_down(p, 16);
        if (quad == 0) out[tok0 + n_in] = p + b3[0];

        // rotate double buffer
#pragma unroll
        for (int kt = 0; kt < 8; ++kt) rawA[kt] = rawB[kt];
    }
}

extern "C" void kernel_launch(void* const* d_in, const int* in_sizes, int n_in,
                              void* d_out, int out_size, void* d_ws, size_t ws_size,
                              hipStream_t stream) {
    const float* x     = (const float*)d_in[0];
    const float* w_ih  = (const float*)d_in[1];
    const float* w_hh  = (const float*)d_in[2];
    const float* b_ih  = (const float*)d_in[3];
    const float* b_hh  = (const float*)d_in[4];
    const float* fc1_w = (const float*)d_in[5];
    const float* fc1_b = (const float*)d_in[6];
    const float* fc2_w = (const float*)d_in[7];
    const float* fc2_b = (const float*)d_in[8];
    const float* fc3_w = (const float*)d_in[9];
    const float* fc3_b = (const float*)d_in[10];

    char* ws = (char*)d_ws;
    _Float16* wsw  = (_Float16*)(ws + WSW_OFF);
    float*    bias = (float*)(ws + BIAS_OFF);
    _Float16* w1f  = (_Float16*)(ws + FC1_OFF);
    _Float16* w2f  = (_Float16*)(ws + FC2_OFF);
    _Float16* hhist= (_Float16*)(ws + HH_OFF);
    unsigned long long* xbuf = (unsigned long long*)(ws + XBUF_OFF);

    k_prep<<<168, 256, 0, stream>>>(w_hh, w_ih, b_ih, b_hh, fc1_w, fc2_w,
                                    wsw, bias, w1f, w2f);
    k_lstm14<<<128, 512, 0, stream>>>(x, wsw, bias, (unsigned*)hhist, xbuf);
    k_mlp5<<<224, 512, 0, stream>>>(hhist, w1f, w2f, fc1_b, fc2_b,
                                    fc3_w, fc3_b, (float*)d_out);
}